// Round 4
// baseline (414.136 us; speedup 1.0000x reference)
//
#include <hip/hip_runtime.h>

typedef unsigned short u16;

#define NGRAPH 16
#define SEQ    1024
#define DIM    128
#define NHEAD  2
#define HDIM   64
#define KPOS   20
#define NTOT   (NGRAPH*SEQ)     // 16384
#define QKVD   (3*DIM)          // 384

// ---------- bf16 helpers ----------------------------------------------------
__device__ __forceinline__ float bf2f(u16 u) {
    return __uint_as_float(((unsigned int)u) << 16);
}
__device__ __forceinline__ u16 f2bf(float f) {
    unsigned int u = __float_as_uint(f);
    u += 0x7fffu + ((u >> 16) & 1u);   // RNE
    return (u16)(u >> 16);
}

// ---------- dtype-adaptive input loads (fbf=1: bf16, fbf=0: f32) -----------
__device__ __forceinline__ float ld1(const void* p, int fbf, size_t i) {
    return fbf ? bf2f(((const u16*)p)[i]) : ((const float*)p)[i];
}
__device__ __forceinline__ void ld8(const void* p, int fbf, size_t i, float* o) {
    if (fbf) {
        float4 v = *(const float4*)((const u16*)p + i);   // 8 bf16
        const u16* u = (const u16*)&v;
#pragma unroll
        for (int j = 0; j < 8; ++j) o[j] = bf2f(u[j]);
    } else {
        const float* q = (const float*)p + i;
        float4 a = *(const float4*)q, b = *(const float4*)(q + 4);
        o[0]=a.x; o[1]=a.y; o[2]=a.z; o[3]=a.w;
        o[4]=b.x; o[5]=b.y; o[6]=b.z; o[7]=b.w;
    }
}

// ---------- K0: dtype detection --------------------------------------------
// bf16 data: even-index u16s are bf16 values of N(0,1) -> exponent in [60,180].
// f32 data: even-index u16s are random mantissa bits -> uniform exponent.
__global__ void detect_kernel(const u16* __restrict__ x, int* __restrict__ flag) {
    if (threadIdx.x == 0 && blockIdx.x == 0) {
        int ok = 1;
        for (int i = 0; i < 256; i += 2) {
            unsigned e = (x[i] >> 7) & 0xFF;
            if (e < 60u || e > 180u) ok = 0;
        }
        *flag = ok;
    }
}

// ---------- K1: h0 = x + pos_enc @ pe_w.T + pe_b  (bf16, strided slots) ----
__global__ __launch_bounds__(256)
void pe_kernel(const void* __restrict__ x, const void* __restrict__ pos,
               const void* __restrict__ pe_w, const void* __restrict__ pe_b,
               u16* __restrict__ h0, const int* __restrict__ flag) {
    int fbf = *flag;
    __shared__ float wsh[DIM][KPOS + 1];
    int t = threadIdx.x;
    for (int i = t; i < DIM * KPOS; i += 256)
        wsh[i / KPOS][i % KPOS] = ld1(pe_w, fbf, i);
    __syncthreads();
    int row = blockIdx.x * 2 + (t >> 7), d = t & 127;
    float acc = 0.f;
#pragma unroll
    for (int k = 0; k < KPOS; ++k)
        acc += ld1(pos, fbf, (size_t)row * KPOS + k) * wsh[d][k];
    int rs = fbf ? 128 : 256;   // h0 row slot stride (u16 units)
    h0[(size_t)row * rs + d] =
        f2bf(ld1(x, fbf, (size_t)row * DIM + d) + acc + ld1(pe_b, fbf, d));
}

// ---------- tiled GEMM: out(rel rows) = A(d_out slots) @ W^T ---------------
// EPI: 0 = +bias, 1 = +bias,relu. A bf16 in d_out slots; W/bias adaptive.
template<int EPI>
__global__ __launch_bounds__(256)
void gemm_kernel(const u16* __restrict__ A, const void* __restrict__ W,
                 const void* __restrict__ bias, u16* __restrict__ out,
                 int K, int Mtot, int row0, const int* __restrict__ flag) {
    int fbf  = *flag;
    int Astr = fbf ? K : 2 * K;       // d_out slot stride (u16 units), K=128
    __shared__ float Ash[64][68];     // [k][row]
    __shared__ float Bsh[64][68];     // [k][m]
    int t  = threadIdx.x;
    int n0 = blockIdx.x * 64;         // relative row tile
    int m0 = blockIdx.y * 64;
    int r0 = (t & 15) * 4;
    int c0 = (t >> 4) * 4;
    float acc[4][4] = {};
    for (int kc = 0; kc < K; kc += 64) {
#pragma unroll
        for (int i = 0; i < 2; ++i) {            // A tile 64x64 bf16
            int idx = t + i * 256;               // 0..511
            int row = idx >> 3, c8 = (idx & 7) * 8;
            float4 av = *(const float4*)&A[(size_t)(row0 + n0 + row) * Astr + kc + c8];
            const u16* au = (const u16*)&av;
#pragma unroll
            for (int j = 0; j < 8; ++j) Ash[c8 + j][row] = bf2f(au[j]);
        }
#pragma unroll
        for (int i = 0; i < 2; ++i) {            // W tile 64x64 adaptive
            int idx = t + i * 256;
            int m = idx >> 3, c8 = (idx & 7) * 8;
            float tmp[8];
            ld8(W, fbf, (size_t)(m0 + m) * K + kc + c8, tmp);
#pragma unroll
            for (int j = 0; j < 8; ++j) Bsh[c8 + j][m] = tmp[j];
        }
        __syncthreads();
#pragma unroll 8
        for (int k = 0; k < 64; ++k) {
            float4 av = *(const float4*)&Ash[k][r0];
            float4 bv = *(const float4*)&Bsh[k][c0];
            float a[4] = {av.x, av.y, av.z, av.w};
            float b[4] = {bv.x, bv.y, bv.z, bv.w};
#pragma unroll
            for (int i = 0; i < 4; ++i)
#pragma unroll
                for (int j = 0; j < 4; ++j)
                    acc[i][j] = fmaf(a[i], b[j], acc[i][j]);
        }
        __syncthreads();
    }
    float bb[4];
#pragma unroll
    for (int j = 0; j < 4; ++j) bb[j] = ld1(bias, fbf, m0 + c0 + j);
#pragma unroll
    for (int i = 0; i < 4; ++i) {
        size_t off = (size_t)(n0 + r0 + i) * Mtot + m0 + c0;
        ushort4 v;
        float o[4];
#pragma unroll
        for (int j = 0; j < 4; ++j) {
            o[j] = acc[i][j] + bb[j];
            if (EPI == 1) o[j] = fmaxf(o[j], 0.f);
        }
        v.x = f2bf(o[0]); v.y = f2bf(o[1]);
        v.z = f2bf(o[2]); v.w = f2bf(o[3]);
        *(ushort4*)&out[off] = v;
    }
}

// ---------- K3: flash attention (bf16 qkv -> bf16 ctx, rel rows) -----------
__global__ __launch_bounds__(256)
void attn_kernel(const u16* __restrict__ qkv, u16* __restrict__ ctx) {
    __shared__ float Qsh[HDIM][64 + 4];
    __shared__ float KPsh[HDIM][64 + 4];
    __shared__ float Vsh[64][HDIM + 4];
    __shared__ float mrow[64], lrow[64], arow[64];
    int t  = threadIdx.x;
    int qt = blockIdx.x, h = blockIdx.y, b = blockIdx.z;
    int q0 = (t & 15) * 4;
    int x0 = (t >> 4) * 4;
#pragma unroll
    for (int i = 0; i < 4; ++i) {
        int idx = t + i * 256;
        int r = idx >> 4, c4 = (idx & 15) * 4;
        size_t n = (size_t)b * SEQ + qt * 64 + r;
        ushort4 v = *(const ushort4*)&qkv[n * QKVD + h * HDIM + c4];
        Qsh[c4 + 0][r] = bf2f(v.x); Qsh[c4 + 1][r] = bf2f(v.y);
        Qsh[c4 + 2][r] = bf2f(v.z); Qsh[c4 + 3][r] = bf2f(v.w);
    }
    if (t < 64) { mrow[t] = -1e30f; lrow[t] = 0.f; }
    float acc[4][4] = {};
    __syncthreads();
    for (int kt = 0; kt < SEQ / 64; ++kt) {
#pragma unroll
        for (int i = 0; i < 4; ++i) {
            int idx = t + i * 256;
            int r = idx >> 4, c4 = (idx & 15) * 4;
            size_t n = (size_t)b * SEQ + kt * 64 + r;
            ushort4 kv = *(const ushort4*)&qkv[n * QKVD + DIM + h * HDIM + c4];
            KPsh[c4 + 0][r] = bf2f(kv.x); KPsh[c4 + 1][r] = bf2f(kv.y);
            KPsh[c4 + 2][r] = bf2f(kv.z); KPsh[c4 + 3][r] = bf2f(kv.w);
            ushort4 vv = *(const ushort4*)&qkv[n * QKVD + 2 * DIM + h * HDIM + c4];
            float4 vf;
            vf.x = bf2f(vv.x); vf.y = bf2f(vv.y);
            vf.z = bf2f(vv.z); vf.w = bf2f(vv.w);
            *(float4*)&Vsh[r][c4] = vf;
        }
        __syncthreads();
        float s[4][4] = {};
#pragma unroll 8
        for (int d = 0; d < HDIM; ++d) {
            float4 av = *(const float4*)&Qsh[d][q0];
            float4 bv = *(const float4*)&KPsh[d][x0];
            float a[4] = {av.x, av.y, av.z, av.w};
            float bb[4] = {bv.x, bv.y, bv.z, bv.w};
#pragma unroll
            for (int i = 0; i < 4; ++i)
#pragma unroll
                for (int j = 0; j < 4; ++j)
                    s[i][j] = fmaf(a[i], bb[j], s[i][j]);
        }
        __syncthreads();
#pragma unroll
        for (int i = 0; i < 4; ++i)
#pragma unroll
            for (int j = 0; j < 4; ++j)
                KPsh[x0 + j][q0 + i] = s[i][j] * 0.125f;   // 1/sqrt(64)
        __syncthreads();
        if (t < 64) {
            float mold = mrow[t], mx = mold;
            for (int k = 0; k < 64; ++k) mx = fmaxf(mx, KPsh[k][t]);
            float al = __expf(mold - mx);
            float sum = 0.f;
            for (int k = 0; k < 64; ++k) {
                float p = __expf(KPsh[k][t] - mx);
                KPsh[k][t] = p;
                sum += p;
            }
            mrow[t] = mx; lrow[t] = lrow[t] * al + sum; arow[t] = al;
        }
        __syncthreads();
        float al[4];
#pragma unroll
        for (int i = 0; i < 4; ++i) al[i] = arow[q0 + i];
#pragma unroll
        for (int i = 0; i < 4; ++i)
#pragma unroll
            for (int j = 0; j < 4; ++j) acc[i][j] *= al[i];
#pragma unroll 8
        for (int k = 0; k < 64; ++k) {
            float4 pv = *(const float4*)&KPsh[k][q0];
            float4 vv = *(const float4*)&Vsh[k][x0];
            float p[4] = {pv.x, pv.y, pv.z, pv.w};
            float v[4] = {vv.x, vv.y, vv.z, vv.w};
#pragma unroll
            for (int i = 0; i < 4; ++i)
#pragma unroll
                for (int j = 0; j < 4; ++j)
                    acc[i][j] = fmaf(p[i], v[j], acc[i][j]);
        }
        __syncthreads();
    }
#pragma unroll
    for (int i = 0; i < 4; ++i) {
        size_t n = (size_t)b * SEQ + qt * 64 + q0 + i;
        float inv = 1.f / lrow[q0 + i];
        ushort4 v;
        v.x = f2bf(acc[i][0] * inv); v.y = f2bf(acc[i][1] * inv);
        v.z = f2bf(acc[i][2] * inv); v.w = f2bf(acc[i][3] * inv);
        *(ushort4*)&ctx[n * DIM + h * HDIM + x0] = v;
    }
}

// ---------- GEMM(64x128 tile) + bias + resid + LayerNorm -------------------
// A: bf16 ws buffer (stride K, rel rows). resid: d_out slots (bf16, stride rs).
// forceBF=1: write bf16 to d_out slots (h1). forceBF=0: final output (per fbf).
__global__ __launch_bounds__(256)
void gemmln_kernel(const u16* __restrict__ A, const void* __restrict__ W,
                   const void* __restrict__ bias, const u16* __restrict__ resid,
                   const void* __restrict__ lng, const void* __restrict__ lnb,
                   void* __restrict__ outp, int K, int row0, int forceBF,
                   const int* __restrict__ flag) {
    int fbf = *flag;
    int rs  = fbf ? 128 : 256;        // d_out slot stride (u16 units)
    __shared__ float Ash[64][68];     // [k][row]
    __shared__ float Bsh[64][132];    // [k][m], later reused as Csh[row][col]
    int t  = threadIdx.x;
    int n0 = blockIdx.x * 64;
    int r0 = (t & 15) * 4;
    int c0 = (t >> 4) * 8;            // 8 cols/thread, covers 128
    float acc[4][8] = {};
    for (int kc = 0; kc < K; kc += 64) {
#pragma unroll
        for (int i = 0; i < 2; ++i) {            // A tile 64x64 bf16
            int idx = t + i * 256;
            int row = idx >> 3, c8 = (idx & 7) * 8;
            float4 av = *(const float4*)&A[(size_t)(n0 + row) * K + kc + c8];
            const u16* au = (const u16*)&av;
#pragma unroll
            for (int j = 0; j < 8; ++j) Ash[c8 + j][row] = bf2f(au[j]);
        }
#pragma unroll
        for (int i = 0; i < 4; ++i) {            // W tile 128x64 adaptive
            int id = t + i * 256;                // 0..1023
            int m = id >> 3, c8 = (id & 7) * 8;
            float tmp[8];
            ld8(W, fbf, (size_t)m * K + kc + c8, tmp);
#pragma unroll
            for (int j = 0; j < 8; ++j) Bsh[c8 + j][m] = tmp[j];
        }
        __syncthreads();
#pragma unroll 8
        for (int k = 0; k < 64; ++k) {
            float4 a4 = *(const float4*)&Ash[k][r0];
            float4 b0 = *(const float4*)&Bsh[k][c0];
            float4 b1 = *(const float4*)&Bsh[k][c0 + 4];
            float a[4] = {a4.x, a4.y, a4.z, a4.w};
            float b[8] = {b0.x, b0.y, b0.z, b0.w, b1.x, b1.y, b1.z, b1.w};
#pragma unroll
            for (int i = 0; i < 4; ++i)
#pragma unroll
                for (int j = 0; j < 8; ++j)
                    acc[i][j] = fmaf(a[i], b[j], acc[i][j]);
        }
        __syncthreads();
    }
    // epilogue: +bias +resid into Csh, then per-row LN
    float bb[8];
    ld8(bias, fbf, c0, bb);
    float (*Csh)[132] = Bsh;
#pragma unroll
    for (int i = 0; i < 4; ++i) {
        size_t rg = (size_t)(row0 + n0 + r0 + i);
        float4 rv4 = *(const float4*)&resid[rg * rs + c0];   // 8 bf16
        const u16* ru = (const u16*)&rv4;
#pragma unroll
        for (int j = 0; j < 8; ++j)
            Csh[r0 + i][c0 + j] = acc[i][j] + bb[j] + bf2f(ru[j]);
    }
    __syncthreads();
#pragma unroll 1
    for (int p = 0; p < 16; ++p) {
        int rowl = p * 4 + (t >> 6);
        int lane = t & 63, c = lane * 2;
        float v0 = Csh[rowl][c], v1 = Csh[rowl][c + 1];
        float s = v0 + v1, sq = v0 * v0 + v1 * v1;
#pragma unroll
        for (int o = 32; o > 0; o >>= 1) {
            s  += __shfl_xor(s, o, 64);
            sq += __shfl_xor(sq, o, 64);
        }
        float mu  = s * (1.f / DIM);
        float var = fmaxf(sq * (1.f / DIM) - mu * mu, 0.f);
        float rsq = rsqrtf(var + 1e-5f);
        float g0 = ld1(lng, fbf, c), g1 = ld1(lng, fbf, c + 1);
        float b0 = ld1(lnb, fbf, c), b1 = ld1(lnb, fbf, c + 1);
        float o0 = (v0 - mu) * rsq * g0 + b0;
        float o1 = (v1 - mu) * rsq * g1 + b1;
        size_t rg = (size_t)(row0 + n0 + rowl);
        if (forceBF) {
            u16* o = (u16*)outp;
            ushort2 w; w.x = f2bf(o0); w.y = f2bf(o1);
            *(ushort2*)&o[rg * rs + c] = w;
        } else if (fbf) {
            u16* o = (u16*)outp;
            ushort2 w; w.x = f2bf(o0); w.y = f2bf(o1);
            *(ushort2*)&o[rg * 128 + c] = w;
        } else {
            float* o = (float*)outp;
            *(float2*)&o[rg * 128 + c] = make_float2(o0, o1);
        }
    }
}

// ---------------------------------------------------------------------------
extern "C" void kernel_launch(void* const* d_in, const int* in_sizes, int n_in,
                              void* d_out, int out_size, void* d_ws, size_t ws_size,
                              hipStream_t stream) {
    const void* x     = d_in[0];
    const void* pos   = d_in[1];
    const void* pe_w  = d_in[2];
    const void* pe_b  = d_in[3];
    const void* in_w  = d_in[4];
    const void* in_b  = d_in[5];
    const void* out_w = d_in[6];
    const void* out_b = d_in[7];
    const void* ln1_g = d_in[8];
    const void* ln1_b = d_in[9];
    const void* ln2_g = d_in[10];
    const void* ln2_b = d_in[11];
    const void* ff1_w = d_in[12];
    const void* ff1_b = d_in[13];
    const void* ff2_w = d_in[14];
    const void* ff2_b = d_in[15];

    char* wsb  = (char*)d_ws;
    int*  flag = (int*)(wsb + ((ws_size - 4) & ~(size_t)3));
    u16*  h01  = (u16*)d_out;   // h0 then h1, bf16 in dtype-dependent row slots
    const size_t MB = 1024 * 1024;

    detect_kernel<<<1, 1, 0, stream>>>((const u16*)x, flag);
    pe_kernel<<<NTOT / 2, 256, 0, stream>>>(x, pos, pe_w, pe_b, h01, flag);

    if (ws_size >= 17 * MB) {
        // batched path: qkv[0,12M), ctx[12M,16M); f1 reuses [0,16M)
        u16* qkv = (u16*)wsb;
        u16* ctx = (u16*)(wsb + 12 * MB);
        u16* f1  = (u16*)wsb;
        gemm_kernel<0><<<dim3(NTOT / 64, QKVD / 64), 256, 0, stream>>>(
            h01, in_w, in_b, qkv, DIM, QKVD, 0, flag);
        attn_kernel<<<dim3(SEQ / 64, NHEAD, NGRAPH), 256, 0, stream>>>(qkv, ctx);
        gemmln_kernel<<<NTOT / 64, 256, 0, stream>>>(
            ctx, out_w, out_b, h01, ln1_g, ln1_b, h01, DIM, 0, 1, flag);
        gemm_kernel<1><<<dim3(NTOT / 64, 8), 256, 0, stream>>>(
            h01, ff1_w, ff1_b, f1, DIM, 4 * DIM, 0, flag);
        gemmln_kernel<<<NTOT / 64, 256, 0, stream>>>(
            f1, ff2_w, ff2_b, h01, ln2_g, ln2_b, d_out, 4 * DIM, 0, 0, flag);
    } else {
        // per-graph path: qkv_g[0,768K), ctx_g[768K,1M); f1_g reuses [0,1M)
        u16* qkv_g = (u16*)wsb;
        u16* ctx_g = (u16*)(wsb + 768 * 1024);
        u16* f1_g  = (u16*)wsb;
        for (int g = 0; g < NGRAPH; ++g) {
            int row0 = g * SEQ;
            gemm_kernel<0><<<dim3(SEQ / 64, QKVD / 64), 256, 0, stream>>>(
                h01, in_w, in_b, qkv_g, DIM, QKVD, row0, flag);
            attn_kernel<<<dim3(SEQ / 64, NHEAD, 1), 256, 0, stream>>>(qkv_g, ctx_g);
            gemmln_kernel<<<SEQ / 64, 256, 0, stream>>>(
                ctx_g, out_w, out_b, h01, ln1_g, ln1_b, h01, DIM, row0, 1, flag);
        }
        for (int g = 0; g < NGRAPH; ++g) {
            int row0 = g * SEQ;
            gemm_kernel<1><<<dim3(SEQ / 64, 8), 256, 0, stream>>>(
                h01, ff1_w, ff1_b, f1_g, DIM, 4 * DIM, row0, flag);
            gemmln_kernel<<<SEQ / 64, 256, 0, stream>>>(
                f1_g, ff2_w, ff2_b, h01, ln2_g, ln2_b, d_out, 4 * DIM, row0, 0, flag);
        }
    }
}

// Round 5
// 317.249 us; speedup vs baseline: 1.3054x; 1.3054x over previous
//
#include <hip/hip_runtime.h>

typedef unsigned short u16;

#define NGRAPH 16
#define SEQ    1024
#define DIM    128
#define NHEAD  2
#define HDIM   64
#define KPOS   20
#define NTOT   (NGRAPH*SEQ)     // 16384
#define QKVD   (3*DIM)          // 384

// ---------- bf16 helpers ----------------------------------------------------
__device__ __forceinline__ float bf2f(u16 u) {
    return __uint_as_float(((unsigned int)u) << 16);
}
__device__ __forceinline__ u16 f2bf(float f) {
    unsigned int u = __float_as_uint(f);
    u += 0x7fffu + ((u >> 16) & 1u);   // RNE
    return (u16)(u >> 16);
}

// ---------- dtype-adaptive input loads (fbf=1: bf16, fbf=0: f32) -----------
__device__ __forceinline__ float ld1(const void* p, int fbf, size_t i) {
    return fbf ? bf2f(((const u16*)p)[i]) : ((const float*)p)[i];
}
__device__ __forceinline__ void ld8(const void* p, int fbf, size_t i, float* o) {
    if (fbf) {
        float4 v = *(const float4*)((const u16*)p + i);   // 8 bf16
        const u16* u = (const u16*)&v;
#pragma unroll
        for (int j = 0; j < 8; ++j) o[j] = bf2f(u[j]);
    } else {
        const float* q = (const float*)p + i;
        float4 a = *(const float4*)q, b = *(const float4*)(q + 4);
        o[0]=a.x; o[1]=a.y; o[2]=a.z; o[3]=a.w;
        o[4]=b.x; o[5]=b.y; o[6]=b.z; o[7]=b.w;
    }
}

// ---------- K0: dtype detection --------------------------------------------
__global__ void detect_kernel(const u16* __restrict__ x, int* __restrict__ flag) {
    if (threadIdx.x == 0 && blockIdx.x == 0) {
        int ok = 1;
        for (int i = 0; i < 256; i += 2) {
            unsigned e = (x[i] >> 7) & 0xFF;
            if (e < 60u || e > 180u) ok = 0;
        }
        *flag = ok;
    }
}

// ---------- K1: h0 = x + pos_enc @ pe_w.T + pe_b  (bf16, strided slots) ----
__global__ __launch_bounds__(256)
void pe_kernel(const void* __restrict__ x, const void* __restrict__ pos,
               const void* __restrict__ pe_w, const void* __restrict__ pe_b,
               u16* __restrict__ h0, const int* __restrict__ flag) {
    int fbf = *flag;
    __shared__ float wsh[DIM][KPOS + 1];
    int t = threadIdx.x;
    for (int i = t; i < DIM * KPOS; i += 256)
        wsh[i / KPOS][i % KPOS] = ld1(pe_w, fbf, i);
    __syncthreads();
    int row = blockIdx.x * 2 + (t >> 7), d = t & 127;
    float acc = 0.f;
#pragma unroll
    for (int k = 0; k < KPOS; ++k)
        acc += ld1(pos, fbf, (size_t)row * KPOS + k) * wsh[d][k];
    int rs = fbf ? 128 : 256;   // h0 row slot stride (u16 units)
    h0[(size_t)row * rs + d] =
        f2bf(ld1(x, fbf, (size_t)row * DIM + d) + acc + ld1(pe_b, fbf, d));
}

// ---------- tiled GEMM: out(rel rows) = A(d_out slots) @ W^T ---------------
// EPI: 0 = +bias, 1 = +bias,relu. A bf16 in d_out slots; W/bias adaptive.
template<int EPI>
__global__ __launch_bounds__(256)
void gemm_kernel(const u16* __restrict__ A, const void* __restrict__ W,
                 const void* __restrict__ bias, u16* __restrict__ out,
                 int K, int Mtot, int row0, const int* __restrict__ flag) {
    int fbf  = *flag;
    int Astr = fbf ? K : 2 * K;       // d_out slot stride (u16 units), K=128
    __shared__ float Ash[64][68];     // [k][row]
    __shared__ float Bsh[64][68];     // [k][m]
    int t  = threadIdx.x;
    int n0 = blockIdx.x * 64;         // relative row tile
    int m0 = blockIdx.y * 64;
    int r0 = (t & 15) * 4;
    int c0 = (t >> 4) * 4;
    float acc[4][4] = {};
    for (int kc = 0; kc < K; kc += 64) {
#pragma unroll
        for (int i = 0; i < 2; ++i) {            // A tile 64x64 bf16
            int idx = t + i * 256;               // 0..511
            int row = idx >> 3, c8 = (idx & 7) * 8;
            float4 av = *(const float4*)&A[(size_t)(row0 + n0 + row) * Astr + kc + c8];
            const u16* au = (const u16*)&av;
#pragma unroll
            for (int j = 0; j < 8; ++j) Ash[c8 + j][row] = bf2f(au[j]);
        }
#pragma unroll
        for (int i = 0; i < 2; ++i) {            // W tile 64x64 adaptive
            int idx = t + i * 256;
            int m = idx >> 3, c8 = (idx & 7) * 8;
            float tmp[8];
            ld8(W, fbf, (size_t)(m0 + m) * K + kc + c8, tmp);
#pragma unroll
            for (int j = 0; j < 8; ++j) Bsh[c8 + j][m] = tmp[j];
        }
        __syncthreads();
#pragma unroll 8
        for (int k = 0; k < 64; ++k) {
            float4 av = *(const float4*)&Ash[k][r0];
            float4 bv = *(const float4*)&Bsh[k][c0];
            float a[4] = {av.x, av.y, av.z, av.w};
            float b[4] = {bv.x, bv.y, bv.z, bv.w};
#pragma unroll
            for (int i = 0; i < 4; ++i)
#pragma unroll
                for (int j = 0; j < 4; ++j)
                    acc[i][j] = fmaf(a[i], b[j], acc[i][j]);
        }
        __syncthreads();
    }
    float bb[4];
#pragma unroll
    for (int j = 0; j < 4; ++j) bb[j] = ld1(bias, fbf, m0 + c0 + j);
#pragma unroll
    for (int i = 0; i < 4; ++i) {
        size_t off = (size_t)(n0 + r0 + i) * Mtot + m0 + c0;
        ushort4 v;
        float o[4];
#pragma unroll
        for (int j = 0; j < 4; ++j) {
            o[j] = acc[i][j] + bb[j];
            if (EPI == 1) o[j] = fmaxf(o[j], 0.f);
        }
        v.x = f2bf(o[0]); v.y = f2bf(o[1]);
        v.z = f2bf(o[2]); v.w = f2bf(o[3]);
        *(ushort4*)&out[off] = v;
    }
}

// ---------- K3: flash attention, MFMA bf16 (qkv bf16 -> ctx bf16) ----------
// grid (SEQ/64, NHEAD, NGRAPH), block 256 = 4 waves. 64-q tile per block,
// wave w owns q-rows [16w,16w+16). 16x16x32 bf16 MFMA for QK^T and PV.
// Layouts (guide §3, m89/m91): A[m=lane&15][k=quad*8+j], B[n=lane&15][k=quad*8+j],
// D[row=quad*4+reg][col=lane&15]. Online softmax stats in registers (wave-private).
typedef __attribute__((ext_vector_type(8))) short bf16x8;
typedef __attribute__((ext_vector_type(4))) float f32x4;

__global__ __launch_bounds__(256)
void attn_kernel(const u16* __restrict__ qkv, u16* __restrict__ ctx) {
    __shared__ u16 Qsh[64][72];    // [q][d]     (+8 pad, rows 144 B: 16B-aligned)
    __shared__ u16 Ksh[64][72];    // [key][d]
    __shared__ u16 VshT[64][72];   // [d][key]
    __shared__ u16 Psh[64][72];    // [q][key]   wave-private row bands
    int t    = threadIdx.x;
    int w    = t >> 6;
    int lane = t & 63;
    int l16  = lane & 15;
    int quad = lane >> 4;
    int qt = blockIdx.x, h = blockIdx.y, b = blockIdx.z;

    // ---- stage Q (64x64 bf16): 2 x float4 per thread, coalesced ----
#pragma unroll
    for (int i = 0; i < 2; ++i) {
        int idx = t + i * 256;               // 0..511
        int r = idx >> 3, d8 = (idx & 7) * 8;
        size_t n = (size_t)b * SEQ + qt * 64 + r;
        float4 v = *(const float4*)&qkv[n * QKVD + h * HDIM + d8];
        *(float4*)&Qsh[r][d8] = v;
    }
    __syncthreads();
    // Q fragments for this wave's 16 rows (kept in regs for all k-tiles)
    bf16x8 qa0 = *(const bf16x8*)&Qsh[w * 16 + l16][quad * 8];
    bf16x8 qa1 = *(const bf16x8*)&Qsh[w * 16 + l16][32 + quad * 8];

    f32x4 o[4] = {};                 // O accum: d-subtile x 4 rows
    float mrow[4] = {-1e30f, -1e30f, -1e30f, -1e30f};
    float lrow[4] = {};

    for (int kt = 0; kt < SEQ / 64; ++kt) {
        // ---- stage K [key][d] ----
#pragma unroll
        for (int i = 0; i < 2; ++i) {
            int idx = t + i * 256;
            int r = idx >> 3, d8 = (idx & 7) * 8;
            size_t n = (size_t)b * SEQ + kt * 64 + r;
            float4 v = *(const float4*)&qkv[n * QKVD + DIM + h * HDIM + d8];
            *(float4*)&Ksh[r][d8] = v;
        }
        // ---- stage V transposed [d][key]: thread t -> key=t&63, d=(t>>6)*16.. ----
        {
            int r = t & 63, dbase = (t >> 6) * 16;
            size_t n = (size_t)b * SEQ + kt * 64 + r;
            float4 va = *(const float4*)&qkv[n * QKVD + 2 * DIM + h * HDIM + dbase];
            float4 vb = *(const float4*)&qkv[n * QKVD + 2 * DIM + h * HDIM + dbase + 8];
            const u16* pa = (const u16*)&va;
            const u16* pb = (const u16*)&vb;
#pragma unroll
            for (int j = 0; j < 8; ++j) VshT[dbase + j][r] = pa[j];
#pragma unroll
            for (int j = 0; j < 8; ++j) VshT[dbase + 8 + j][r] = pb[j];
        }
        __syncthreads();

        // ---- S = Q K^T for this wave's 16-row band (4 key-subtiles) ----
        float sc[4][4];
#pragma unroll
        for (int c = 0; c < 4; ++c) {
            bf16x8 kb0 = *(const bf16x8*)&Ksh[c * 16 + l16][quad * 8];
            bf16x8 kb1 = *(const bf16x8*)&Ksh[c * 16 + l16][32 + quad * 8];
            f32x4 s = {};
            s = __builtin_amdgcn_mfma_f32_16x16x32_bf16(qa0, kb0, s, 0, 0, 0);
            s = __builtin_amdgcn_mfma_f32_16x16x32_bf16(qa1, kb1, s, 0, 0, 0);
#pragma unroll
            for (int r = 0; r < 4; ++r) sc[c][r] = s[r] * 0.125f; // 1/sqrt(64)
        }
        // ---- online softmax (rows = quad*4+reg, cols = c*16+l16) ----
        float alpha[4];
#pragma unroll
        for (int r = 0; r < 4; ++r) {
            float mx = fmaxf(fmaxf(sc[0][r], sc[1][r]), fmaxf(sc[2][r], sc[3][r]));
#pragma unroll
            for (int off = 1; off < 16; off <<= 1)
                mx = fmaxf(mx, __shfl_xor(mx, off, 64));
            float mnew = fmaxf(mrow[r], mx);
            alpha[r] = __expf(mrow[r] - mnew);
            mrow[r] = mnew;
            float sum = 0.f;
#pragma unroll
            for (int c = 0; c < 4; ++c) {
                float p = __expf(sc[c][r] - mnew);
                sc[c][r] = p;
                sum += p;
            }
#pragma unroll
            for (int off = 1; off < 16; off <<= 1)
                sum += __shfl_xor(sum, off, 64);
            lrow[r] = lrow[r] * alpha[r] + sum;
        }
        // ---- write P (bf16) to wave-private band of Psh; rescale O ----
#pragma unroll
        for (int c = 0; c < 4; ++c)
#pragma unroll
            for (int r = 0; r < 4; ++r)
                Psh[w * 16 + quad * 4 + r][c * 16 + l16] = f2bf(sc[c][r]);
#pragma unroll
        for (int dt = 0; dt < 4; ++dt)
#pragma unroll
            for (int r = 0; r < 4; ++r) o[dt][r] *= alpha[r];
        // ---- O += P V  (A = P band, B = V^T) ----
        bf16x8 pa0 = *(const bf16x8*)&Psh[w * 16 + l16][quad * 8];
        bf16x8 pa1 = *(const bf16x8*)&Psh[w * 16 + l16][32 + quad * 8];
#pragma unroll
        for (int dt = 0; dt < 4; ++dt) {
            bf16x8 vb0 = *(const bf16x8*)&VshT[dt * 16 + l16][quad * 8];
            bf16x8 vb1 = *(const bf16x8*)&VshT[dt * 16 + l16][32 + quad * 8];
            o[dt] = __builtin_amdgcn_mfma_f32_16x16x32_bf16(pa0, vb0, o[dt], 0, 0, 0);
            o[dt] = __builtin_amdgcn_mfma_f32_16x16x32_bf16(pa1, vb1, o[dt], 0, 0, 0);
        }
        __syncthreads();   // protect Ksh/VshT before next tile's staging
    }
    // ---- epilogue: O/l -> ctx (row = qt*64 + w*16 + quad*4 + r) ----
#pragma unroll
    for (int r = 0; r < 4; ++r) {
        float inv = 1.f / lrow[r];
        size_t n = (size_t)b * SEQ + qt * 64 + w * 16 + quad * 4 + r;
#pragma unroll
        for (int dt = 0; dt < 4; ++dt)
            ctx[n * DIM + h * HDIM + dt * 16 + l16] = f2bf(o[dt][r] * inv);
    }
}

// ---------- GEMM(64x128 tile) + bias + resid + LayerNorm -------------------
__global__ __launch_bounds__(256)
void gemmln_kernel(const u16* __restrict__ A, const void* __restrict__ W,
                   const void* __restrict__ bias, const u16* __restrict__ resid,
                   const void* __restrict__ lng, const void* __restrict__ lnb,
                   void* __restrict__ outp, int K, int row0, int forceBF,
                   const int* __restrict__ flag) {
    int fbf = *flag;
    int rs  = fbf ? 128 : 256;        // d_out slot stride (u16 units)
    __shared__ float Ash[64][68];     // [k][row]
    __shared__ float Bsh[64][132];    // [k][m], later reused as Csh[row][col]
    int t  = threadIdx.x;
    int n0 = blockIdx.x * 64;
    int r0 = (t & 15) * 4;
    int c0 = (t >> 4) * 8;            // 8 cols/thread, covers 128
    float acc[4][8] = {};
    for (int kc = 0; kc < K; kc += 64) {
#pragma unroll
        for (int i = 0; i < 2; ++i) {            // A tile 64x64 bf16
            int idx = t + i * 256;
            int row = idx >> 3, c8 = (idx & 7) * 8;
            float4 av = *(const float4*)&A[(size_t)(n0 + row) * K + kc + c8];
            const u16* au = (const u16*)&av;
#pragma unroll
            for (int j = 0; j < 8; ++j) Ash[c8 + j][row] = bf2f(au[j]);
        }
#pragma unroll
        for (int i = 0; i < 4; ++i) {            // W tile 128x64 adaptive
            int id = t + i * 256;                // 0..1023
            int m = id >> 3, c8 = (id & 7) * 8;
            float tmp[8];
            ld8(W, fbf, (size_t)m * K + kc + c8, tmp);
#pragma unroll
            for (int j = 0; j < 8; ++j) Bsh[c8 + j][m] = tmp[j];
        }
        __syncthreads();
#pragma unroll 8
        for (int k = 0; k < 64; ++k) {
            float4 a4 = *(const float4*)&Ash[k][r0];
            float4 b0 = *(const float4*)&Bsh[k][c0];
            float4 b1 = *(const float4*)&Bsh[k][c0 + 4];
            float a[4] = {a4.x, a4.y, a4.z, a4.w};
            float b[8] = {b0.x, b0.y, b0.z, b0.w, b1.x, b1.y, b1.z, b1.w};
#pragma unroll
            for (int i = 0; i < 4; ++i)
#pragma unroll
                for (int j = 0; j < 8; ++j)
                    acc[i][j] = fmaf(a[i], b[j], acc[i][j]);
        }
        __syncthreads();
    }
    // epilogue: +bias +resid into Csh, then per-row LN
    float bb[8];
    ld8(bias, fbf, c0, bb);
    float (*Csh)[132] = Bsh;
#pragma unroll
    for (int i = 0; i < 4; ++i) {
        size_t rg = (size_t)(row0 + n0 + r0 + i);
        float4 rv4 = *(const float4*)&resid[rg * rs + c0];   // 8 bf16
        const u16* ru = (const u16*)&rv4;
#pragma unroll
        for (int j = 0; j < 8; ++j)
            Csh[r0 + i][c0 + j] = acc[i][j] + bb[j] + bf2f(ru[j]);
    }
    __syncthreads();
#pragma unroll 1
    for (int p = 0; p < 16; ++p) {
        int rowl = p * 4 + (t >> 6);
        int lane = t & 63, c = lane * 2;
        float v0 = Csh[rowl][c], v1 = Csh[rowl][c + 1];
        float s = v0 + v1, sq = v0 * v0 + v1 * v1;
#pragma unroll
        for (int o = 32; o > 0; o >>= 1) {
            s  += __shfl_xor(s, o, 64);
            sq += __shfl_xor(sq, o, 64);
        }
        float mu  = s * (1.f / DIM);
        float var = fmaxf(sq * (1.f / DIM) - mu * mu, 0.f);
        float rsq = rsqrtf(var + 1e-5f);
        float g0 = ld1(lng, fbf, c), g1 = ld1(lng, fbf, c + 1);
        float b0 = ld1(lnb, fbf, c), b1 = ld1(lnb, fbf, c + 1);
        float o0 = (v0 - mu) * rsq * g0 + b0;
        float o1 = (v1 - mu) * rsq * g1 + b1;
        size_t rg = (size_t)(row0 + n0 + rowl);
        if (forceBF) {
            u16* o = (u16*)outp;
            ushort2 w; w.x = f2bf(o0); w.y = f2bf(o1);
            *(ushort2*)&o[rg * rs + c] = w;
        } else if (fbf) {
            u16* o = (u16*)outp;
            ushort2 w; w.x = f2bf(o0); w.y = f2bf(o1);
            *(ushort2*)&o[rg * 128 + c] = w;
        } else {
            float* o = (float*)outp;
            *(float2*)&o[rg * 128 + c] = make_float2(o0, o1);
        }
    }
}

// ---------------------------------------------------------------------------
extern "C" void kernel_launch(void* const* d_in, const int* in_sizes, int n_in,
                              void* d_out, int out_size, void* d_ws, size_t ws_size,
                              hipStream_t stream) {
    const void* x     = d_in[0];
    const void* pos   = d_in[1];
    const void* pe_w  = d_in[2];
    const void* pe_b  = d_in[3];
    const void* in_w  = d_in[4];
    const void* in_b  = d_in[5];
    const void* out_w = d_in[6];
    const void* out_b = d_in[7];
    const void* ln1_g = d_in[8];
    const void* ln1_b = d_in[9];
    const void* ln2_g = d_in[10];
    const void* ln2_b = d_in[11];
    const void* ff1_w = d_in[12];
    const void* ff1_b = d_in[13];
    const void* ff2_w = d_in[14];
    const void* ff2_b = d_in[15];

    char* wsb  = (char*)d_ws;
    int*  flag = (int*)(wsb + ((ws_size - 4) & ~(size_t)3));
    u16*  h01  = (u16*)d_out;   // h0 then h1, bf16 in dtype-dependent row slots
    const size_t MB = 1024 * 1024;

    detect_kernel<<<1, 1, 0, stream>>>((const u16*)x, flag);
    pe_kernel<<<NTOT / 2, 256, 0, stream>>>(x, pos, pe_w, pe_b, h01, flag);

    if (ws_size >= 17 * MB) {
        // batched path: qkv[0,12M), ctx[12M,16M); f1 reuses [0,16M)
        u16* qkv = (u16*)wsb;
        u16* ctx = (u16*)(wsb + 12 * MB);
        u16* f1  = (u16*)wsb;
        gemm_kernel<0><<<dim3(NTOT / 64, QKVD / 64), 256, 0, stream>>>(
            h01, in_w, in_b, qkv, DIM, QKVD, 0, flag);
        attn_kernel<<<dim3(SEQ / 64, NHEAD, NGRAPH), 256, 0, stream>>>(qkv, ctx);
        gemmln_kernel<<<NTOT / 64, 256, 0, stream>>>(
            ctx, out_w, out_b, h01, ln1_g, ln1_b, h01, DIM, 0, 1, flag);
        gemm_kernel<1><<<dim3(NTOT / 64, 8), 256, 0, stream>>>(
            h01, ff1_w, ff1_b, f1, DIM, 4 * DIM, 0, flag);
        gemmln_kernel<<<NTOT / 64, 256, 0, stream>>>(
            f1, ff2_w, ff2_b, h01, ln2_g, ln2_b, d_out, 4 * DIM, 0, 0, flag);
    } else {
        // per-graph path: qkv_g[0,768K), ctx_g[768K,1M); f1_g reuses [0,1M)
        u16* qkv_g = (u16*)wsb;
        u16* ctx_g = (u16*)(wsb + 768 * 1024);
        u16* f1_g  = (u16*)wsb;
        for (int g = 0; g < NGRAPH; ++g) {
            int row0 = g * SEQ;
            gemm_kernel<0><<<dim3(SEQ / 64, QKVD / 64), 256, 0, stream>>>(
                h01, in_w, in_b, qkv_g, DIM, QKVD, row0, flag);
            attn_kernel<<<dim3(SEQ / 64, NHEAD, 1), 256, 0, stream>>>(qkv_g, ctx_g);
            gemmln_kernel<<<SEQ / 64, 256, 0, stream>>>(
                ctx_g, out_w, out_b, h01, ln1_g, ln1_b, h01, DIM, row0, 1, flag);
        }
        for (int g = 0; g < NGRAPH; ++g) {
            int row0 = g * SEQ;
            gemm_kernel<1><<<dim3(SEQ / 64, 8), 256, 0, stream>>>(
                h01, ff1_w, ff1_b, f1_g, DIM, 4 * DIM, row0, flag);
            gemmln_kernel<<<SEQ / 64, 256, 0, stream>>>(
                f1_g, ff2_w, ff2_b, h01, ln2_g, ln2_b, d_out, 4 * DIM, row0, 0, flag);
        }
    }
}

// Round 6
// 223.143 us; speedup vs baseline: 1.8559x; 1.4217x over previous
//
#include <hip/hip_runtime.h>

typedef unsigned short u16;

#define NGRAPH 16
#define SEQ    1024
#define DIM    128
#define NHEAD  2
#define HDIM   64
#define KPOS   20
#define NTOT   (NGRAPH*SEQ)     // 16384
#define QKVD   (3*DIM)          // 384

// ---------- bf16 helpers ----------------------------------------------------
__device__ __forceinline__ float bf2f(u16 u) {
    return __uint_as_float(((unsigned int)u) << 16);
}
__device__ __forceinline__ u16 f2bf(float f) {
    unsigned int u = __float_as_uint(f);
    u += 0x7fffu + ((u >> 16) & 1u);   // RNE
    return (u16)(u >> 16);
}

// ---------- dtype-adaptive input loads (fbf=1: bf16, fbf=0: f32) -----------
__device__ __forceinline__ float ld1(const void* p, int fbf, size_t i) {
    return fbf ? bf2f(((const u16*)p)[i]) : ((const float*)p)[i];
}

// ---------- K0: dtype detection --------------------------------------------
__global__ void detect_kernel(const u16* __restrict__ x, int* __restrict__ flag) {
    if (threadIdx.x == 0 && blockIdx.x == 0) {
        int ok = 1;
        for (int i = 0; i < 256; i += 2) {
            unsigned e = (x[i] >> 7) & 0xFF;
            if (e < 60u || e > 180u) ok = 0;
        }
        *flag = ok;
    }
}

// ---------- K1: h0 = x + pos_enc @ pe_w.T + pe_b  (bf16, strided slots) ----
__global__ __launch_bounds__(256)
void pe_kernel(const void* __restrict__ x, const void* __restrict__ pos,
               const void* __restrict__ pe_w, const void* __restrict__ pe_b,
               u16* __restrict__ h0, const int* __restrict__ flag) {
    int fbf = *flag;
    __shared__ float wsh[DIM][KPOS + 1];
    int t = threadIdx.x;
    for (int i = t; i < DIM * KPOS; i += 256)
        wsh[i / KPOS][i % KPOS] = ld1(pe_w, fbf, i);
    __syncthreads();
    int row = blockIdx.x * 2 + (t >> 7), d = t & 127;
    float acc = 0.f;
#pragma unroll
    for (int k = 0; k < KPOS; ++k)
        acc += ld1(pos, fbf, (size_t)row * KPOS + k) * wsh[d][k];
    int rs = fbf ? 128 : 256;   // h0 row slot stride (u16 units)
    h0[(size_t)row * rs + d] =
        f2bf(ld1(x, fbf, (size_t)row * DIM + d) + acc + ld1(pe_b, fbf, d));
}

typedef __attribute__((ext_vector_type(8))) short bf16x8;
typedef __attribute__((ext_vector_type(4))) float f32x4;

// ---------- unified MFMA GEMM: out = A @ W^T (+epilogue) -------------------
// Block 256 = 4 waves; tile 64 rows x 128 cols; wave w owns rows [16w,16w+16).
// EPI 0: +bias -> bf16 ws (stride Mtot)      EPI 1: +bias,relu -> bf16 ws
// EPI 2: +bias+resid+LN -> h01 slots (rs)    EPI 3: +bias+resid+LN -> final out
// A is always bf16; Astr<0 means "h01 slot stride" (fbf?128:256).
// arow0: global row base for A; orow0: global row base for resid/out (EPI>=2).
template<int EPI>
__global__ __launch_bounds__(256)
void mgemm_kernel(const u16* __restrict__ A, const void* __restrict__ W,
                  const void* __restrict__ bias, const u16* __restrict__ resid,
                  const void* __restrict__ lng, const void* __restrict__ lnb,
                  void* __restrict__ outp, int K, int Mtot, int AstrIn,
                  int arow0, int orow0, const int* __restrict__ flag) {
    int fbf  = *flag;
    int rs   = fbf ? 128 : 256;
    int Astr = (AstrIn < 0) ? rs : AstrIn;
    __shared__ u16 Ash[64][72];    // [row][k]  (+8 pad; rows 144 B, 16B-aligned)
    __shared__ u16 Wsh[128][72];   // [col][k]
    int t = threadIdx.x;
    int w = t >> 6, lane = t & 63, l16 = lane & 15, quad = lane >> 4;
    int n0 = blockIdx.x * 64;
    int m0 = blockIdx.y * 128;
    f32x4 acc[8] = {};
    for (int kc = 0; kc < K; kc += 64) {
        // ---- stage A 64x64 bf16: direct float4 copies ----
#pragma unroll
        for (int i = 0; i < 2; ++i) {
            int idx = t + i * 256;           // 0..511
            int row = idx >> 3, k8 = (idx & 7) * 8;
            *(float4*)&Ash[row][k8] =
                *(const float4*)&A[(size_t)(arow0 + n0 + row) * Astr + kc + k8];
        }
        // ---- stage W 128x64 (adaptive dtype) ----
#pragma unroll
        for (int i = 0; i < 4; ++i) {
            int idx = t + i * 256;           // 0..1023
            int m = idx >> 3, k8 = (idx & 7) * 8;
            if (fbf) {
                *(float4*)&Wsh[m][k8] =
                    *(const float4*)&((const u16*)W)[(size_t)(m0 + m) * K + kc + k8];
            } else {
                const float* q = (const float*)W + (size_t)(m0 + m) * K + kc + k8;
                float4 a = *(const float4*)q, b = *(const float4*)(q + 4);
                u16* d = &Wsh[m][k8];
                d[0]=f2bf(a.x); d[1]=f2bf(a.y); d[2]=f2bf(a.z); d[3]=f2bf(a.w);
                d[4]=f2bf(b.x); d[5]=f2bf(b.y); d[6]=f2bf(b.z); d[7]=f2bf(b.w);
            }
        }
        __syncthreads();
        // ---- MFMA: 2 k32-chunks x 8 col-subtiles ----
#pragma unroll
        for (int kk = 0; kk < 2; ++kk) {
            bf16x8 af = *(const bf16x8*)&Ash[w * 16 + l16][kk * 32 + quad * 8];
#pragma unroll
            for (int s = 0; s < 8; ++s) {
                bf16x8 bf = *(const bf16x8*)&Wsh[s * 16 + l16][kk * 32 + quad * 8];
                acc[s] = __builtin_amdgcn_mfma_f32_16x16x32_bf16(af, bf, acc[s], 0, 0, 0);
            }
        }
        __syncthreads();
    }
    // ---- epilogue ----
    float bb[8];
#pragma unroll
    for (int s = 0; s < 8; ++s) bb[s] = ld1(bias, fbf, m0 + s * 16 + l16);
    float gg[8], be[8];
    if (EPI >= 2) {
#pragma unroll
        for (int s = 0; s < 8; ++s) {
            gg[s] = ld1(lng, fbf, s * 16 + l16);
            be[s] = ld1(lnb, fbf, s * 16 + l16);
        }
    }
#pragma unroll
    for (int r = 0; r < 4; ++r) {
        int lr = w * 16 + quad * 4 + r;      // local row in tile
        float v[8];
#pragma unroll
        for (int s = 0; s < 8; ++s) {
            v[s] = acc[s][r] + bb[s];
            if (EPI == 1) v[s] = fmaxf(v[s], 0.f);
        }
        if (EPI <= 1) {
            u16* o = (u16*)outp;
#pragma unroll
            for (int s = 0; s < 8; ++s)
                o[(size_t)(n0 + lr) * Mtot + m0 + s * 16 + l16] = f2bf(v[s]);
        } else {
            size_t rg = (size_t)(orow0 + n0 + lr);
#pragma unroll
            for (int s = 0; s < 8; ++s)
                v[s] += bf2f(resid[rg * rs + s * 16 + l16]);
            float sm = 0.f, sq = 0.f;
#pragma unroll
            for (int s = 0; s < 8; ++s) { sm += v[s]; sq += v[s] * v[s]; }
#pragma unroll
            for (int off = 1; off < 16; off <<= 1) {
                sm += __shfl_xor(sm, off, 64);
                sq += __shfl_xor(sq, off, 64);
            }
            float mu  = sm * (1.f / DIM);
            float var = fmaxf(sq * (1.f / DIM) - mu * mu, 0.f);
            float rsq = rsqrtf(var + 1e-5f);
            if (EPI == 2) {
                u16* o = (u16*)outp;
#pragma unroll
                for (int s = 0; s < 8; ++s)
                    o[rg * rs + s * 16 + l16] =
                        f2bf((v[s] - mu) * rsq * gg[s] + be[s]);
            } else {
                if (fbf) {
                    u16* o = (u16*)outp;
#pragma unroll
                    for (int s = 0; s < 8; ++s)
                        o[rg * 128 + s * 16 + l16] =
                            f2bf((v[s] - mu) * rsq * gg[s] + be[s]);
                } else {
                    float* o = (float*)outp;
#pragma unroll
                    for (int s = 0; s < 8; ++s)
                        o[rg * 128 + s * 16 + l16] =
                            (v[s] - mu) * rsq * gg[s] + be[s];
                }
            }
        }
    }
}

// ---------- K3: flash attention, MFMA bf16 (qkv bf16 -> ctx bf16) ----------
__global__ __launch_bounds__(256)
void attn_kernel(const u16* __restrict__ qkv, u16* __restrict__ ctx) {
    __shared__ u16 Qsh[64][72];
    __shared__ u16 Ksh[64][72];
    __shared__ u16 VshT[64][72];
    __shared__ u16 Psh[64][72];
    int t    = threadIdx.x;
    int w    = t >> 6;
    int lane = t & 63;
    int l16  = lane & 15;
    int quad = lane >> 4;
    int qt = blockIdx.x, h = blockIdx.y, b = blockIdx.z;

#pragma unroll
    for (int i = 0; i < 2; ++i) {
        int idx = t + i * 256;
        int r = idx >> 3, d8 = (idx & 7) * 8;
        size_t n = (size_t)b * SEQ + qt * 64 + r;
        *(float4*)&Qsh[r][d8] = *(const float4*)&qkv[n * QKVD + h * HDIM + d8];
    }
    __syncthreads();
    bf16x8 qa0 = *(const bf16x8*)&Qsh[w * 16 + l16][quad * 8];
    bf16x8 qa1 = *(const bf16x8*)&Qsh[w * 16 + l16][32 + quad * 8];

    f32x4 o[4] = {};
    float mrow[4] = {-1e30f, -1e30f, -1e30f, -1e30f};
    float lrow[4] = {};

    for (int kt = 0; kt < SEQ / 64; ++kt) {
#pragma unroll
        for (int i = 0; i < 2; ++i) {
            int idx = t + i * 256;
            int r = idx >> 3, d8 = (idx & 7) * 8;
            size_t n = (size_t)b * SEQ + kt * 64 + r;
            *(float4*)&Ksh[r][d8] =
                *(const float4*)&qkv[n * QKVD + DIM + h * HDIM + d8];
        }
        {
            int r = t & 63, dbase = (t >> 6) * 16;
            size_t n = (size_t)b * SEQ + kt * 64 + r;
            float4 va = *(const float4*)&qkv[n * QKVD + 2 * DIM + h * HDIM + dbase];
            float4 vb = *(const float4*)&qkv[n * QKVD + 2 * DIM + h * HDIM + dbase + 8];
            const u16* pa = (const u16*)&va;
            const u16* pb = (const u16*)&vb;
#pragma unroll
            for (int j = 0; j < 8; ++j) VshT[dbase + j][r] = pa[j];
#pragma unroll
            for (int j = 0; j < 8; ++j) VshT[dbase + 8 + j][r] = pb[j];
        }
        __syncthreads();

        float sc[4][4];
#pragma unroll
        for (int c = 0; c < 4; ++c) {
            bf16x8 kb0 = *(const bf16x8*)&Ksh[c * 16 + l16][quad * 8];
            bf16x8 kb1 = *(const bf16x8*)&Ksh[c * 16 + l16][32 + quad * 8];
            f32x4 s = {};
            s = __builtin_amdgcn_mfma_f32_16x16x32_bf16(qa0, kb0, s, 0, 0, 0);
            s = __builtin_amdgcn_mfma_f32_16x16x32_bf16(qa1, kb1, s, 0, 0, 0);
#pragma unroll
            for (int r = 0; r < 4; ++r) sc[c][r] = s[r] * 0.125f;
        }
        float alpha[4];
#pragma unroll
        for (int r = 0; r < 4; ++r) {
            float mx = fmaxf(fmaxf(sc[0][r], sc[1][r]), fmaxf(sc[2][r], sc[3][r]));
#pragma unroll
            for (int off = 1; off < 16; off <<= 1)
                mx = fmaxf(mx, __shfl_xor(mx, off, 64));
            float mnew = fmaxf(mrow[r], mx);
            alpha[r] = __expf(mrow[r] - mnew);
            mrow[r] = mnew;
            float sum = 0.f;
#pragma unroll
            for (int c = 0; c < 4; ++c) {
                float p = __expf(sc[c][r] - mnew);
                sc[c][r] = p;
                sum += p;
            }
#pragma unroll
            for (int off = 1; off < 16; off <<= 1)
                sum += __shfl_xor(sum, off, 64);
            lrow[r] = lrow[r] * alpha[r] + sum;
        }
#pragma unroll
        for (int c = 0; c < 4; ++c)
#pragma unroll
            for (int r = 0; r < 4; ++r)
                Psh[w * 16 + quad * 4 + r][c * 16 + l16] = f2bf(sc[c][r]);
#pragma unroll
        for (int dt = 0; dt < 4; ++dt)
#pragma unroll
            for (int r = 0; r < 4; ++r) o[dt][r] *= alpha[r];
        bf16x8 pa0 = *(const bf16x8*)&Psh[w * 16 + l16][quad * 8];
        bf16x8 pa1 = *(const bf16x8*)&Psh[w * 16 + l16][32 + quad * 8];
#pragma unroll
        for (int dt = 0; dt < 4; ++dt) {
            bf16x8 vb0 = *(const bf16x8*)&VshT[dt * 16 + l16][quad * 8];
            bf16x8 vb1 = *(const bf16x8*)&VshT[dt * 16 + l16][32 + quad * 8];
            o[dt] = __builtin_amdgcn_mfma_f32_16x16x32_bf16(pa0, vb0, o[dt], 0, 0, 0);
            o[dt] = __builtin_amdgcn_mfma_f32_16x16x32_bf16(pa1, vb1, o[dt], 0, 0, 0);
        }
        __syncthreads();
    }
#pragma unroll
    for (int r = 0; r < 4; ++r) {
        float inv = 1.f / lrow[r];
        size_t n = (size_t)b * SEQ + qt * 64 + w * 16 + quad * 4 + r;
#pragma unroll
        for (int dt = 0; dt < 4; ++dt)
            ctx[n * DIM + h * HDIM + dt * 16 + l16] = f2bf(o[dt][r] * inv);
    }
}

// ---------------------------------------------------------------------------
extern "C" void kernel_launch(void* const* d_in, const int* in_sizes, int n_in,
                              void* d_out, int out_size, void* d_ws, size_t ws_size,
                              hipStream_t stream) {
    const void* x     = d_in[0];
    const void* pos   = d_in[1];
    const void* pe_w  = d_in[2];
    const void* pe_b  = d_in[3];
    const void* in_w  = d_in[4];
    const void* in_b  = d_in[5];
    const void* out_w = d_in[6];
    const void* out_b = d_in[7];
    const void* ln1_g = d_in[8];
    const void* ln1_b = d_in[9];
    const void* ln2_g = d_in[10];
    const void* ln2_b = d_in[11];
    const void* ff1_w = d_in[12];
    const void* ff1_b = d_in[13];
    const void* ff2_w = d_in[14];
    const void* ff2_b = d_in[15];

    char* wsb  = (char*)d_ws;
    int*  flag = (int*)(wsb + ((ws_size - 4) & ~(size_t)3));
    u16*  h01  = (u16*)d_out;   // h0 then h1, bf16 in dtype-dependent row slots
    const size_t MB = 1024 * 1024;

    detect_kernel<<<1, 1, 0, stream>>>((const u16*)x, flag);
    pe_kernel<<<NTOT / 2, 256, 0, stream>>>(x, pos, pe_w, pe_b, h01, flag);

    if (ws_size >= 17 * MB) {
        // batched path: qkv[0,12M), ctx[12M,16M); f1 reuses [0,16M)
        u16* qkv = (u16*)wsb;
        u16* ctx = (u16*)(wsb + 12 * MB);
        u16* f1  = (u16*)wsb;
        mgemm_kernel<0><<<dim3(NTOT / 64, 3), 256, 0, stream>>>(
            h01, in_w, in_b, nullptr, nullptr, nullptr, qkv,
            DIM, QKVD, -1, 0, 0, flag);
        attn_kernel<<<dim3(SEQ / 64, NHEAD, NGRAPH), 256, 0, stream>>>(qkv, ctx);
        mgemm_kernel<2><<<dim3(NTOT / 64, 1), 256, 0, stream>>>(
            ctx, out_w, out_b, h01, ln1_g, ln1_b, h01,
            DIM, DIM, DIM, 0, 0, flag);
        mgemm_kernel<1><<<dim3(NTOT / 64, 4), 256, 0, stream>>>(
            h01, ff1_w, ff1_b, nullptr, nullptr, nullptr, f1,
            DIM, 4 * DIM, -1, 0, 0, flag);
        mgemm_kernel<3><<<dim3(NTOT / 64, 1), 256, 0, stream>>>(
            f1, ff2_w, ff2_b, h01, ln2_g, ln2_b, d_out,
            4 * DIM, DIM, 4 * DIM, 0, 0, flag);
    } else {
        // per-graph path: qkv_g[0,768K), ctx_g[768K,1M); f1_g reuses [0,1M)
        u16* qkv_g = (u16*)wsb;
        u16* ctx_g = (u16*)(wsb + 768 * 1024);
        u16* f1_g  = (u16*)wsb;
        for (int g = 0; g < NGRAPH; ++g) {
            int row0 = g * SEQ;
            mgemm_kernel<0><<<dim3(SEQ / 64, 3), 256, 0, stream>>>(
                h01, in_w, in_b, nullptr, nullptr, nullptr, qkv_g,
                DIM, QKVD, -1, row0, 0, flag);
            attn_kernel<<<dim3(SEQ / 64, NHEAD, 1), 256, 0, stream>>>(qkv_g, ctx_g);
            mgemm_kernel<2><<<dim3(SEQ / 64, 1), 256, 0, stream>>>(
                ctx_g, out_w, out_b, h01, ln1_g, ln1_b, h01,
                DIM, DIM, DIM, 0, row0, flag);
        }
        for (int g = 0; g < NGRAPH; ++g) {
            int row0 = g * SEQ;
            mgemm_kernel<1><<<dim3(SEQ / 64, 4), 256, 0, stream>>>(
                h01, ff1_w, ff1_b, nullptr, nullptr, nullptr, f1_g,
                DIM, 4 * DIM, -1, row0, 0, flag);
            mgemm_kernel<3><<<dim3(SEQ / 64, 1), 256, 0, stream>>>(
                f1_g, ff2_w, ff2_b, h01, ln2_g, ln2_b, d_out,
                4 * DIM, DIM, 4 * DIM, 0, row0, flag);
        }
    }
}

// Round 7
// 222.632 us; speedup vs baseline: 1.8602x; 1.0023x over previous
//
#include <hip/hip_runtime.h>

typedef unsigned short u16;

#define NGRAPH 16
#define SEQ    1024
#define DIM    128
#define NHEAD  2
#define HDIM   64
#define KPOS   20
#define NTOT   (NGRAPH*SEQ)     // 16384
#define QKVD   (3*DIM)          // 384

// ---------- bf16 helpers ----------------------------------------------------
__device__ __forceinline__ float bf2f(u16 u) {
    return __uint_as_float(((unsigned int)u) << 16);
}
__device__ __forceinline__ u16 f2bf(float f) {
    unsigned int u = __float_as_uint(f);
    u += 0x7fffu + ((u >> 16) & 1u);   // RNE
    return (u16)(u >> 16);
}

// ---------- dtype-adaptive input loads (fbf=1: bf16, fbf=0: f32) -----------
__device__ __forceinline__ float ld1(const void* p, int fbf, size_t i) {
    return fbf ? bf2f(((const u16*)p)[i]) : ((const float*)p)[i];
}
// 8 contiguous weights -> packed bf16x8 (as float4 bit pattern)
__device__ __forceinline__ float4 ldw8(const void* W, int fbf, size_t i) {
    if (fbf) return *(const float4*)((const u16*)W + i);
    const float* q = (const float*)W + i;
    float4 a = *(const float4*)q, b = *(const float4*)(q + 4);
    float4 r;
    u16* d = (u16*)&r;
    d[0]=f2bf(a.x); d[1]=f2bf(a.y); d[2]=f2bf(a.z); d[3]=f2bf(a.w);
    d[4]=f2bf(b.x); d[5]=f2bf(b.y); d[6]=f2bf(b.z); d[7]=f2bf(b.w);
    return r;
}

// ---------- K0: dtype detection --------------------------------------------
__global__ void detect_kernel(const u16* __restrict__ x, int* __restrict__ flag) {
    if (threadIdx.x == 0 && blockIdx.x == 0) {
        int ok = 1;
        for (int i = 0; i < 256; i += 2) {
            unsigned e = (x[i] >> 7) & 0xFF;
            if (e < 60u || e > 180u) ok = 0;
        }
        *flag = ok;
    }
}

// ---------- K1: h0 = x + pos_enc @ pe_w.T + pe_b  (bf16, strided slots) ----
__global__ __launch_bounds__(256)
void pe_kernel(const void* __restrict__ x, const void* __restrict__ pos,
               const void* __restrict__ pe_w, const void* __restrict__ pe_b,
               u16* __restrict__ h0, const int* __restrict__ flag) {
    int fbf = *flag;
    __shared__ float wsh[DIM][KPOS + 1];
    int t = threadIdx.x;
    for (int i = t; i < DIM * KPOS; i += 256)
        wsh[i / KPOS][i % KPOS] = ld1(pe_w, fbf, i);
    __syncthreads();
    int row = blockIdx.x * 2 + (t >> 7), d = t & 127;
    float acc = 0.f;
#pragma unroll
    for (int k = 0; k < KPOS; ++k)
        acc += ld1(pos, fbf, (size_t)row * KPOS + k) * wsh[d][k];
    int rs = fbf ? 128 : 256;   // h0 row slot stride (u16 units)
    h0[(size_t)row * rs + d] =
        f2bf(ld1(x, fbf, (size_t)row * DIM + d) + acc + ld1(pe_b, fbf, d));
}

typedef __attribute__((ext_vector_type(8))) short bf16x8;
typedef __attribute__((ext_vector_type(4))) float f32x4;

// ---------- unified MFMA GEMM: out = A @ W^T (+epilogue) -------------------
// Block 256 = 4 waves; tile 64 rows x 128 cols; K staged 128 at a time
// (NK chunks of 128), register-prefetched. One barrier per chunk.
// EPI 0: +bias -> bf16 ws     EPI 1: +bias,relu -> bf16 ws
// EPI 2: +bias+resid+LN -> h01 slots   EPI 3: +bias+resid+LN -> final out
// A always bf16; AstrIn<0 means "h01 slot stride" (fbf?128:256).
template<int EPI, int NK>
__global__ __launch_bounds__(256)
void mgemm_kernel(const u16* __restrict__ A, const void* __restrict__ W,
                  const void* __restrict__ bias, const u16* __restrict__ resid,
                  const void* __restrict__ lng, const void* __restrict__ lnb,
                  void* __restrict__ outp, int Mtot, int AstrIn,
                  int arow0, int orow0, const int* __restrict__ flag) {
    const int K = NK * 128;
    int fbf  = *flag;
    int rs   = fbf ? 128 : 256;
    int Astr = (AstrIn < 0) ? rs : AstrIn;
    __shared__ u16 Ash[64][136];    // [row][k] (+8 pad)
    __shared__ u16 Wsh[128][136];   // [col][k]
    int t = threadIdx.x;
    int w = t >> 6, lane = t & 63, l16 = lane & 15, quad = lane >> 4;
    int n0 = blockIdx.x * 64;
    int m0 = blockIdx.y * 128;
    f32x4 acc[8] = {};
    float4 aR[4], wR[8];
    // prefetch chunk 0
#pragma unroll
    for (int i = 0; i < 4; ++i) {
        int idx = t + i * 256;
        int row = idx >> 4, k8 = (idx & 15) * 8;
        aR[i] = *(const float4*)&A[(size_t)(arow0 + n0 + row) * Astr + k8];
    }
#pragma unroll
    for (int i = 0; i < 8; ++i) {
        int idx = t + i * 256;
        int row = idx >> 4, k8 = (idx & 15) * 8;
        wR[i] = ldw8(W, fbf, (size_t)(m0 + row) * K + k8);
    }
#pragma unroll 1
    for (int c = 0; c < NK; ++c) {
        // regs -> LDS
#pragma unroll
        for (int i = 0; i < 4; ++i) {
            int idx = t + i * 256;
            *(float4*)&Ash[idx >> 4][(idx & 15) * 8] = aR[i];
        }
#pragma unroll
        for (int i = 0; i < 8; ++i) {
            int idx = t + i * 256;
            *(float4*)&Wsh[idx >> 4][(idx & 15) * 8] = wR[i];
        }
        __syncthreads();
        if (c + 1 < NK) {   // prefetch next chunk (overlaps MFMA below)
            int kc = (c + 1) * 128;
#pragma unroll
            for (int i = 0; i < 4; ++i) {
                int idx = t + i * 256;
                int row = idx >> 4, k8 = (idx & 15) * 8;
                aR[i] = *(const float4*)&A[(size_t)(arow0 + n0 + row) * Astr + kc + k8];
            }
#pragma unroll
            for (int i = 0; i < 8; ++i) {
                int idx = t + i * 256;
                int row = idx >> 4, k8 = (idx & 15) * 8;
                wR[i] = ldw8(W, fbf, (size_t)(m0 + row) * K + kc + k8);
            }
        }
#pragma unroll
        for (int kk = 0; kk < 4; ++kk) {
            bf16x8 af = *(const bf16x8*)&Ash[w * 16 + l16][kk * 32 + quad * 8];
#pragma unroll
            for (int s = 0; s < 8; ++s) {
                bf16x8 bf = *(const bf16x8*)&Wsh[s * 16 + l16][kk * 32 + quad * 8];
                acc[s] = __builtin_amdgcn_mfma_f32_16x16x32_bf16(af, bf, acc[s], 0, 0, 0);
            }
        }
        if (c + 1 < NK) __syncthreads();
    }
    // ---- epilogue ----
    float bb[8];
#pragma unroll
    for (int s = 0; s < 8; ++s) bb[s] = ld1(bias, fbf, m0 + s * 16 + l16);
    float gg[8], be[8];
    if (EPI >= 2) {
#pragma unroll
        for (int s = 0; s < 8; ++s) {
            gg[s] = ld1(lng, fbf, s * 16 + l16);
            be[s] = ld1(lnb, fbf, s * 16 + l16);
        }
    }
#pragma unroll
    for (int r = 0; r < 4; ++r) {
        int lr = w * 16 + quad * 4 + r;
        float v[8];
#pragma unroll
        for (int s = 0; s < 8; ++s) {
            v[s] = acc[s][r] + bb[s];
            if (EPI == 1) v[s] = fmaxf(v[s], 0.f);
        }
        if (EPI <= 1) {
            u16* o = (u16*)outp;
#pragma unroll
            for (int s = 0; s < 8; ++s)
                o[(size_t)(n0 + lr) * Mtot + m0 + s * 16 + l16] = f2bf(v[s]);
        } else {
            size_t rg = (size_t)(orow0 + n0 + lr);
#pragma unroll
            for (int s = 0; s < 8; ++s)
                v[s] += bf2f(resid[rg * rs + s * 16 + l16]);
            float sm = 0.f, sq = 0.f;
#pragma unroll
            for (int s = 0; s < 8; ++s) { sm += v[s]; sq += v[s] * v[s]; }
#pragma unroll
            for (int off = 1; off < 16; off <<= 1) {
                sm += __shfl_xor(sm, off, 64);
                sq += __shfl_xor(sq, off, 64);
            }
            float mu  = sm * (1.f / DIM);
            float var = fmaxf(sq * (1.f / DIM) - mu * mu, 0.f);
            float rsq = rsqrtf(var + 1e-5f);
            if (EPI == 2) {
                u16* o = (u16*)outp;
#pragma unroll
                for (int s = 0; s < 8; ++s)
                    o[rg * rs + s * 16 + l16] =
                        f2bf((v[s] - mu) * rsq * gg[s] + be[s]);
            } else {
                if (fbf) {
                    u16* o = (u16*)outp;
#pragma unroll
                    for (int s = 0; s < 8; ++s)
                        o[rg * 128 + s * 16 + l16] =
                            f2bf((v[s] - mu) * rsq * gg[s] + be[s]);
                } else {
                    float* o = (float*)outp;
#pragma unroll
                    for (int s = 0; s < 8; ++s)
                        o[rg * 128 + s * 16 + l16] =
                            (v[s] - mu) * rsq * gg[s] + be[s];
                }
            }
        }
    }
}

// ---------- K3: flash attention, MFMA bf16, pipelined K/V staging ----------
// 1D grid = ngh*16 blocks (ngh = graphs*heads). For ngh>=8, blockIdx is
// XCD-swizzled so all 16 q-tiles of one graph-head land on one XCD (its K/V
// then stays in that XCD's L2). Reg-prefetch of next K/V tile overlaps compute.
__global__ __launch_bounds__(256)
void attn_kernel(const u16* __restrict__ qkv, u16* __restrict__ ctx) {
    __shared__ u16 Qsh[64][72];
    __shared__ u16 Ksh[64][72];
    __shared__ u16 VshT[64][72];
    __shared__ u16 Psh[64][72];
    int t    = threadIdx.x;
    int w    = t >> 6;
    int lane = t & 63;
    int l16  = lane & 15;
    int quad = lane >> 4;
    int L = blockIdx.x;
    int ngh = gridDim.x >> 4;
    int qt, gh;
    if (ngh >= 8) {           // XCD swizzle: L%8 selects XCD -> gh%8
        int g8 = L & 7; int rest = L >> 3;
        qt = rest & 15; gh = (rest >> 4) * 8 + g8;
    } else {
        qt = L & 15; gh = L >> 4;
    }
    int b = gh >> 1, h = gh & 1;

    // ---- stage Q ----
#pragma unroll
    for (int i = 0; i < 2; ++i) {
        int idx = t + i * 256;
        int r = idx >> 3, d8 = (idx & 7) * 8;
        size_t n = (size_t)b * SEQ + qt * 64 + r;
        *(float4*)&Qsh[r][d8] = *(const float4*)&qkv[n * QKVD + h * HDIM + d8];
    }
    // ---- prefetch K/V tile 0 into regs ----
    int kr = t >> 3, kd8 = (t & 7) * 8;          // K: rows 0..31 (i=0), 32..63 (i=1)
    int vr = t & 63, vdb = (t >> 6) * 16;        // V: key, d-base
    float4 kR[2], vR[2];
    {
        size_t nk0 = (size_t)b * SEQ + kr;
        kR[0] = *(const float4*)&qkv[nk0 * QKVD + DIM + h * HDIM + kd8];
        kR[1] = *(const float4*)&qkv[(nk0 + 32) * QKVD + DIM + h * HDIM + kd8];
        size_t nv0 = (size_t)b * SEQ + vr;
        vR[0] = *(const float4*)&qkv[nv0 * QKVD + 2 * DIM + h * HDIM + vdb];
        vR[1] = *(const float4*)&qkv[nv0 * QKVD + 2 * DIM + h * HDIM + vdb + 8];
    }
    __syncthreads();
    bf16x8 qa0 = *(const bf16x8*)&Qsh[w * 16 + l16][quad * 8];
    bf16x8 qa1 = *(const bf16x8*)&Qsh[w * 16 + l16][32 + quad * 8];

    f32x4 o[4] = {};
    float mrow[4] = {-1e30f, -1e30f, -1e30f, -1e30f};
    float lrow[4] = {};

#pragma unroll 1
    for (int kt = 0; kt < SEQ / 64; ++kt) {
        // ---- regs -> LDS ----
        *(float4*)&Ksh[kr][kd8]      = kR[0];
        *(float4*)&Ksh[kr + 32][kd8] = kR[1];
        {
            const u16* pa = (const u16*)&vR[0];
            const u16* pb = (const u16*)&vR[1];
#pragma unroll
            for (int j = 0; j < 8; ++j) VshT[vdb + j][vr] = pa[j];
#pragma unroll
            for (int j = 0; j < 8; ++j) VshT[vdb + 8 + j][vr] = pb[j];
        }
        __syncthreads();
        if (kt + 1 < SEQ / 64) {   // prefetch next tile (overlaps compute)
            size_t nk0 = (size_t)b * SEQ + (kt + 1) * 64 + kr;
            kR[0] = *(const float4*)&qkv[nk0 * QKVD + DIM + h * HDIM + kd8];
            kR[1] = *(const float4*)&qkv[(nk0 + 32) * QKVD + DIM + h * HDIM + kd8];
            size_t nv0 = (size_t)b * SEQ + (kt + 1) * 64 + vr;
            vR[0] = *(const float4*)&qkv[nv0 * QKVD + 2 * DIM + h * HDIM + vdb];
            vR[1] = *(const float4*)&qkv[nv0 * QKVD + 2 * DIM + h * HDIM + vdb + 8];
        }

        float sc[4][4];
#pragma unroll
        for (int c = 0; c < 4; ++c) {
            bf16x8 kb0 = *(const bf16x8*)&Ksh[c * 16 + l16][quad * 8];
            bf16x8 kb1 = *(const bf16x8*)&Ksh[c * 16 + l16][32 + quad * 8];
            f32x4 s = {};
            s = __builtin_amdgcn_mfma_f32_16x16x32_bf16(qa0, kb0, s, 0, 0, 0);
            s = __builtin_amdgcn_mfma_f32_16x16x32_bf16(qa1, kb1, s, 0, 0, 0);
#pragma unroll
            for (int r = 0; r < 4; ++r) sc[c][r] = s[r] * 0.125f;
        }
        float alpha[4];
#pragma unroll
        for (int r = 0; r < 4; ++r) {
            float mx = fmaxf(fmaxf(sc[0][r], sc[1][r]), fmaxf(sc[2][r], sc[3][r]));
#pragma unroll
            for (int off = 1; off < 16; off <<= 1)
                mx = fmaxf(mx, __shfl_xor(mx, off, 64));
            float mnew = fmaxf(mrow[r], mx);
            alpha[r] = __expf(mrow[r] - mnew);
            mrow[r] = mnew;
            float sum = 0.f;
#pragma unroll
            for (int c = 0; c < 4; ++c) {
                float p = __expf(sc[c][r] - mnew);
                sc[c][r] = p;
                sum += p;
            }
#pragma unroll
            for (int off = 1; off < 16; off <<= 1)
                sum += __shfl_xor(sum, off, 64);
            lrow[r] = lrow[r] * alpha[r] + sum;
        }
#pragma unroll
        for (int c = 0; c < 4; ++c)
#pragma unroll
            for (int r = 0; r < 4; ++r)
                Psh[w * 16 + quad * 4 + r][c * 16 + l16] = f2bf(sc[c][r]);
#pragma unroll
        for (int dt = 0; dt < 4; ++dt)
#pragma unroll
            for (int r = 0; r < 4; ++r) o[dt][r] *= alpha[r];
        bf16x8 pa0 = *(const bf16x8*)&Psh[w * 16 + l16][quad * 8];
        bf16x8 pa1 = *(const bf16x8*)&Psh[w * 16 + l16][32 + quad * 8];
#pragma unroll
        for (int dt = 0; dt < 4; ++dt) {
            bf16x8 vb0 = *(const bf16x8*)&VshT[dt * 16 + l16][quad * 8];
            bf16x8 vb1 = *(const bf16x8*)&VshT[dt * 16 + l16][32 + quad * 8];
            o[dt] = __builtin_amdgcn_mfma_f32_16x16x32_bf16(pa0, vb0, o[dt], 0, 0, 0);
            o[dt] = __builtin_amdgcn_mfma_f32_16x16x32_bf16(pa1, vb1, o[dt], 0, 0, 0);
        }
        __syncthreads();
    }
#pragma unroll
    for (int r = 0; r < 4; ++r) {
        float inv = 1.f / lrow[r];
        size_t n = (size_t)b * SEQ + qt * 64 + w * 16 + quad * 4 + r;
#pragma unroll
        for (int dt = 0; dt < 4; ++dt)
            ctx[n * DIM + h * HDIM + dt * 16 + l16] = f2bf(o[dt][r] * inv);
    }
}

// ---------------------------------------------------------------------------
extern "C" void kernel_launch(void* const* d_in, const int* in_sizes, int n_in,
                              void* d_out, int out_size, void* d_ws, size_t ws_size,
                              hipStream_t stream) {
    const void* x     = d_in[0];
    const void* pos   = d_in[1];
    const void* pe_w  = d_in[2];
    const void* pe_b  = d_in[3];
    const void* in_w  = d_in[4];
    const void* in_b  = d_in[5];
    const void* out_w = d_in[6];
    const void* out_b = d_in[7];
    const void* ln1_g = d_in[8];
    const void* ln1_b = d_in[9];
    const void* ln2_g = d_in[10];
    const void* ln2_b = d_in[11];
    const void* ff1_w = d_in[12];
    const void* ff1_b = d_in[13];
    const void* ff2_w = d_in[14];
    const void* ff2_b = d_in[15];

    char* wsb  = (char*)d_ws;
    int*  flag = (int*)(wsb + ((ws_size - 4) & ~(size_t)3));
    u16*  h01  = (u16*)d_out;   // h0 then h1, bf16 in dtype-dependent row slots
    const size_t MB = 1024 * 1024;

    detect_kernel<<<1, 1, 0, stream>>>((const u16*)x, flag);
    pe_kernel<<<NTOT / 2, 256, 0, stream>>>(x, pos, pe_w, pe_b, h01, flag);

    if (ws_size >= 17 * MB) {
        // batched path: qkv[0,12M), ctx[12M,16M); f1 reuses [0,16M)
        u16* qkv = (u16*)wsb;
        u16* ctx = (u16*)(wsb + 12 * MB);
        u16* f1  = (u16*)wsb;
        mgemm_kernel<0,1><<<dim3(NTOT / 64, 3), 256, 0, stream>>>(
            h01, in_w, in_b, nullptr, nullptr, nullptr, qkv,
            QKVD, -1, 0, 0, flag);
        attn_kernel<<<NGRAPH * NHEAD * 16, 256, 0, stream>>>(qkv, ctx);
        mgemm_kernel<2,1><<<dim3(NTOT / 64, 1), 256, 0, stream>>>(
            ctx, out_w, out_b, h01, ln1_g, ln1_b, h01,
            DIM, DIM, 0, 0, flag);
        mgemm_kernel<1,1><<<dim3(NTOT / 64, 4), 256, 0, stream>>>(
            h01, ff1_w, ff1_b, nullptr, nullptr, nullptr, f1,
            4 * DIM, -1, 0, 0, flag);
        mgemm_kernel<3,4><<<dim3(NTOT / 64, 1), 256, 0, stream>>>(
            f1, ff2_w, ff2_b, h01, ln2_g, ln2_b, d_out,
            DIM, 4 * DIM, 0, 0, flag);
    } else {
        // per-graph path: qkv_g[0,768K), ctx_g[768K,1M); f1_g reuses [0,1M)
        u16* qkv_g = (u16*)wsb;
        u16* ctx_g = (u16*)(wsb + 768 * 1024);
        u16* f1_g  = (u16*)wsb;
        for (int g = 0; g < NGRAPH; ++g) {
            int row0 = g * SEQ;
            mgemm_kernel<0,1><<<dim3(SEQ / 64, 3), 256, 0, stream>>>(
                h01, in_w, in_b, nullptr, nullptr, nullptr, qkv_g,
                QKVD, -1, row0, 0, flag);
            attn_kernel<<<NHEAD * 16, 256, 0, stream>>>(qkv_g, ctx_g);
            mgemm_kernel<2,1><<<dim3(SEQ / 64, 1), 256, 0, stream>>>(
                ctx_g, out_w, out_b, h01, ln1_g, ln1_b, h01,
                DIM, DIM, 0, row0, flag);
        }
        for (int g = 0; g < NGRAPH; ++g) {
            int row0 = g * SEQ;
            mgemm_kernel<1,1><<<dim3(SEQ / 64, 4), 256, 0, stream>>>(
                h01, ff1_w, ff1_b, nullptr, nullptr, nullptr, f1_g,
                4 * DIM, -1, row0, 0, flag);
            mgemm_kernel<3,4><<<dim3(SEQ / 64, 1), 256, 0, stream>>>(
                f1_g, ff2_w, ff2_b, h01, ln2_g, ln2_b, d_out,
                DIM, 4 * DIM, 0, row0, flag);
        }
    }
}